// Round 4
// baseline (517.603 us; speedup 1.0000x reference)
//
#include <hip/hip_runtime.h>

#define E_EDGES 20000
#define D_DIM   128
#define HSLICES 132           // 128 W2 rows + bias row + 3 zero rows
#define NPAIRS  66            // h-pairs 0..65 (pair 64 = (bias,0), 65 = (0,0))

// prep grid layout
#define NBA 132               // W2/b2 repack: one h-slice per block
#define NBH 313               // hidden: ceil(20000/64) edge-blocks
#define NBC 320               // h_w fp32->bf16, grid-stride

typedef __bf16 bf16x8 __attribute__((ext_vector_type(8)));
typedef float  floatx4 __attribute__((ext_vector_type(4)));

__device__ __forceinline__ unsigned short f32_to_bf16_rne(float f) {
    unsigned int u = __float_as_uint(f);
    unsigned int r = u + 0x7FFFu + ((u >> 16) & 1u);
    return (unsigned short)(r >> 16);
}

__device__ __forceinline__ void gload_lds16(const void* g, void* l) {
    __builtin_amdgcn_global_load_lds(
        (const __attribute__((address_space(1))) unsigned int*)g,
        (__attribute__((address_space(3))) unsigned int*)l, 16, 0, 0);
}

// ---------------------------------------------------------------------------
// Fused prep.
// Part A: repack one h-slice of W2 (h==128: b2; h>=129: zeros) into
//   fragment-major bf16 bpf via padded LDS transpose. Chunk cidx in [0,2048):
//   ll=cidx&63, s'=(cidx>>6)&1, g'=(cidx>>7)&3, ks=(cidx>>9)&1, ch=(cidx>>10)&1
//   col = 64ch+16g'+(ll&15), k0 = 64ks+32s'+8(ll>>4); elem j: B_h[k0+j][col].
// Part B: hiddenT bf16-PAIRS hTp[p][e]; W1/b1 through the scalar path
//   (readfirstlane-pinned uniform index). Pair 64 = (1,0), 65 = (0,0).
// Part C: h_w fp32 -> bf16 [e][j].
// ---------------------------------------------------------------------------
__global__ __launch_bounds__(256) void prep_all(
    const float* __restrict__ W2, const float* __restrict__ b2,
    const float* __restrict__ ef, const float* __restrict__ W1,
    const float* __restrict__ b1, const float* __restrict__ hw,
    uint4* __restrict__ bpf, unsigned int* __restrict__ hTp,
    unsigned short* __restrict__ hwb)
{
    __shared__ __align__(16) char pmem[34816];   // A: 128 x 136 ushort; B: 64 x 17 float
    const int bx = blockIdx.x;
    const int t  = threadIdx.x;

    if (bx < NBA) {
        const int h = bx;
        if (h < 129) {
            unsigned short* tile = (unsigned short*)pmem;   // [col][136]
            const float* src = (h < 128) ? (W2 + (size_t)h * (D_DIM * D_DIM)) : b2;
            #pragma unroll
            for (int r = 0; r < 16; ++r) {
                const float4 v = ((const float4*)src)[r * 256 + t];
                int c   = (r * 256 + t) * 4;
                int col = c >> 7;
                int k   = c & 127;
                unsigned int u0 = f32_to_bf16_rne(v.x) | ((unsigned int)f32_to_bf16_rne(v.y) << 16);
                unsigned int u1 = f32_to_bf16_rne(v.z) | ((unsigned int)f32_to_bf16_rne(v.w) << 16);
                *(uint2*)&tile[col * 136 + k] = make_uint2(u0, u1);
            }
            __syncthreads();
            #pragma unroll
            for (int r2 = 0; r2 < 8; ++r2) {
                int cidx = r2 * 256 + t;
                int ll = cidx & 63;
                int sp = (cidx >> 6) & 1;
                int gp = (cidx >> 7) & 3;
                int ks = (cidx >> 9) & 1;
                int ch = (cidx >> 10) & 1;
                int col = 64 * ch + 16 * gp + (ll & 15);
                int k0  = 64 * ks + 32 * sp + 8 * (ll >> 4);
                bpf[(size_t)h * 2048 + cidx] = *(const uint4*)&tile[col * 136 + k0];
            }
        } else {
            #pragma unroll
            for (int r2 = 0; r2 < 8; ++r2)
                bpf[(size_t)h * 2048 + r2 * 256 + t] = make_uint4(0, 0, 0, 0);
        }
    } else if (bx < NBA + NBH) {
        float (*lds_ef)[17] = (float(*)[17])pmem;
        const int b  = bx - NBA;
        const int e0 = b * 64;
        {   // stage ef coalesced: thread t -> edge t/4, feature quad t%4
            int e  = t >> 2;
            int k4 = (t & 3) * 4;
            int ge = e0 + e;
            float4 v = make_float4(0.f, 0.f, 0.f, 0.f);
            if (ge < E_EDGES) v = *(const float4*)(ef + (size_t)ge * 16 + k4);
            lds_ef[e][k4 + 0] = v.x; lds_ef[e][k4 + 1] = v.y;
            lds_ef[e][k4 + 2] = v.z; lds_ef[e][k4 + 3] = v.w;
        }
        __syncthreads();
        const int e  = t & 63;
        const int hg = t >> 6;                // wave-uniform
        const bool valid = (e0 + e) < E_EDGES;
        float efr[16];
        #pragma unroll
        for (int k = 0; k < 16; ++k) efr[k] = lds_ef[e][k];
        #pragma unroll 4
        for (int hi2 = 0; hi2 < 16; ++hi2) {
            // pin the row index to an SGPR so W1/b1 go through s_load
            const int h0 = __builtin_amdgcn_readfirstlane(hg * 32 + 2 * hi2);
            float a0 = b1[h0], a1 = b1[h0 + 1];
            #pragma unroll
            for (int k = 0; k < 16; ++k) {
                a0 += efr[k] * W1[k * 128 + h0];
                a1 += efr[k] * W1[k * 128 + h0 + 1];
            }
            unsigned int pk = (unsigned int)f32_to_bf16_rne(fmaxf(a0, 0.f))
                            | ((unsigned int)f32_to_bf16_rne(fmaxf(a1, 0.f)) << 16);
            if (valid) hTp[(size_t)(hg * 16 + hi2) * E_EDGES + e0 + e] = pk;
        }
        if (hg == 0 && valid) {
            hTp[(size_t)64 * E_EDGES + e0 + e] = 0x00003F80u;   // (bf16 1.0, 0)
            hTp[(size_t)65 * E_EDGES + e0 + e] = 0u;            // (0, 0)
        }
    } else {
        int i0 = (bx - NBA - NBH) * 256 + t;
        for (int i = i0; i < (E_EDGES * D_DIM) / 4; i += NBC * 256) {
            const float4 v = ((const float4*)hw)[i];
            union { unsigned short u16[4]; uint2 u2; } o;
            o.u16[0] = f32_to_bf16_rne(v.x);
            o.u16[1] = f32_to_bf16_rne(v.y);
            o.u16[2] = f32_to_bf16_rne(v.z);
            o.u16[3] = f32_to_bf16_rne(v.w);
            ((uint2*)hwb)[i] = o.u2;
        }
    }
}

// ---------------------------------------------------------------------------
// Main: 504 blocks x 512 threads (4 idle). Block = 160 edges x 64 cols x 64 j
// (K-split). ks=bx&1, ch=(bx>>2)&1 are XCD-constant (bx%8 fixes both) ->
// per-XCD B working set = 132 x 8KB = 1.06 MB in L2. eg=(bx>>3)*2+((bx>>1)&1).
// 2 blocks/CU (LDS 64KB, VGPR<=128) -> 16 waves/CU. Phases of 4 h-steps:
// stage 4 B-slices (32KB) via global_load_lds dbuf; hidden as bf16 pairs.
// Partial sums combined across ks via fp32 atomicAdd onto zeroed d_out.
// ---------------------------------------------------------------------------
__global__ __launch_bounds__(512, 4)
void edge_main(const uint4* __restrict__ bpf, const unsigned int* __restrict__ hTp,
               const uint4* __restrict__ hwb, float* __restrict__ out) {
    __shared__ __align__(16) char smem[65536];   // 2 bufs x (4 h-slices x 8KB)
    const int bx  = blockIdx.x;
    const int ch  = (bx >> 2) & 1;
    const int ks  = bx & 1;
    const int eg  = (bx >> 3) * 2 + ((bx >> 1) & 1);
    if (eg >= 125) return;
    const int tid = threadIdx.x;
    const int w   = tid >> 6;
    const int l   = tid & 63;
    const int l4  = l >> 4;
    const int lm  = l & 15;
    const int g   = w & 3;
    const int eh  = w >> 2;
    const int e0  = eg * 160;
    const int eA  = e0 + eh * 80;

    // resident A frags (j-half ks): A[m][s'] = hw[eA+16m+lm][64ks+32s'+8*l4 ..+7]
    bf16x8 A[5][2];
    #pragma unroll
    for (int m = 0; m < 5; ++m)
        #pragma unroll
        for (int sp = 0; sp < 2; ++sp)
            A[m][sp] = ((const bf16x8*)hwb)[(eA + 16 * m + lm) * 16 + 8 * ks + 4 * sp + l4];

    floatx4 C[5];
    #pragma unroll
    for (int m = 0; m < 5; ++m) C[m] = (floatx4){0.f, 0.f, 0.f, 0.f};
    const floatx4 Zf = (floatx4){0.f, 0.f, 0.f, 0.f};

    const char* bpf_c = (const char*)bpf;

    auto stage = [&](int q, int p) {              // stage 4 h-slices of phase q
        #pragma unroll
        for (int r = 0; r < 4; ++r) {
            const int flat = w * 4 + r;           // wave-uniform, [0,32)
            const int hh   = flat >> 3;
            const int off  = (flat & 7) * 1024;
            const char* src = bpf_c + (size_t)(4 * q + hh) * 32768
                            + ch * 16384 + ks * 8192 + off;
            char* dst = smem + p * 32768 + hh * 8192 + off;
            gload_lds16(src + l * 16, dst);
        }
    };
    auto loadHP2 = [&](int q, uint4 (&hq)[2][5]) {
        #pragma unroll
        for (int pp = 0; pp < 2; ++pp) {
            const unsigned int* row = hTp + (size_t)(2 * q + pp) * E_EDGES + eA + 4 * l4;
            #pragma unroll
            for (int m = 0; m < 5; ++m) hq[pp][m] = *(const uint4*)(row + 16 * m);
        }
    };
    auto computeH = [&](int p, int hh, const uint4 (&hp)[5], bool odd) {
        const char* slice = smem + p * 32768 + hh * 8192;
        bf16x8 B[2];
        #pragma unroll
        for (int sp = 0; sp < 2; ++sp)
            B[sp] = *(const bf16x8*)(slice + (g * 2 + sp) * 1024 + l * 16);
        #pragma unroll
        for (int m = 0; m < 5; ++m) {
            floatx4 D = __builtin_amdgcn_mfma_f32_16x16x32_bf16(A[m][0], B[0], Zf, 0, 0, 0);
            D = __builtin_amdgcn_mfma_f32_16x16x32_bf16(A[m][1], B[1], D, 0, 0, 0);
            #pragma unroll
            for (int r = 0; r < 4; ++r) {
                unsigned int u = hp[m][r];
                float sc = odd ? __uint_as_float(u & 0xFFFF0000u)
                               : __uint_as_float(u << 16);
                C[m][r] += sc * D[r];
            }
        }
    };

    uint4 hq[2][5];
    stage(0, 0);
    for (int q = 0; q < 33; ++q) {
        __syncthreads();                  // phase-q staging drained (vmcnt(0))
        if (q < 32) stage(q + 1, (q + 1) & 1);
        loadHP2(q, hq);
        const int p = q & 1;
        computeH(p, 0, hq[0], false);     // h = 4q
        computeH(p, 1, hq[0], true);      // h = 4q+1
        computeH(p, 2, hq[1], false);     // h = 4q+2
        computeH(p, 3, hq[1], true);      // h = 4q+3
    }

    // epilogue: C/D layout col = lane&15, row = 4*(lane>>4)+r ; combine K-split
    #pragma unroll
    for (int m = 0; m < 5; ++m)
        #pragma unroll
        for (int r = 0; r < 4; ++r)
            atomicAdd(&out[(size_t)(eA + 16 * m + 4 * l4 + r) * D_DIM
                           + 64 * ch + 16 * g + lm], C[m][r]);
}

// ---------------------------------------------------------------------------
extern "C" void kernel_launch(void* const* d_in, const int* in_sizes, int n_in,
                              void* d_out, int out_size, void* d_ws, size_t ws_size,
                              hipStream_t stream) {
    // inputs: h_v, h_w, edge_features, W1, b1, W2, b2 (fp32; h_v unused)
    const float* h_w = (const float*)d_in[1];
    const float* ef  = (const float*)d_in[2];
    const float* W1  = (const float*)d_in[3];
    const float* b1  = (const float*)d_in[4];
    const float* W2  = (const float*)d_in[5];
    const float* b2  = (const float*)d_in[6];
    float* out = (float*)d_out;

    char* ws = (char*)d_ws;
    uint4*          bpf = (uint4*)ws;                                  // 132*32768 = 4,325,376 B
    unsigned int*   hTp = (unsigned int*)(ws + 4325376);               // 66*20000*4 = 5,280,000 B
    unsigned short* hwb = (unsigned short*)(ws + 4325376 + 5280000);   // 5,120,000 B
    // total ws use: 14,725,376 B

    hipLaunchKernelGGL(prep_all, dim3(NBA + NBH + NBC), dim3(256), 0, stream,
                       W2, b2, ef, W1, b1, h_w, bpf, hTp, hwb);
    hipMemsetAsync(out, 0, (size_t)out_size * sizeof(float), stream);
    hipLaunchKernelGGL(edge_main, dim3(504), dim3(512), 0, stream,
                       bpf, hTp, (const uint4*)hwb, out);
}

// Round 5
// 187.645 us; speedup vs baseline: 2.7584x; 2.7584x over previous
//
#include <hip/hip_runtime.h>

#define E_EDGES 20000
#define D_DIM   128
#define SLAB_DW 5376          // per-eg hidden slab stride: 21504 B (66 pairs x 80 e x 4B, padded)

// prep grid layout
#define NBA 132               // W2/b2 repack: one h-slice per block (128 W2 + bias + 3 zero)
#define NBH 313               // hidden: ceil(20000/64) edge-blocks
#define NBC 320               // h_w fp32->bf16, grid-stride
#define NBD 250               // zero d_out, grid-stride

typedef __bf16 bf16x8 __attribute__((ext_vector_type(8)));
typedef float  floatx4 __attribute__((ext_vector_type(4)));

__device__ __forceinline__ unsigned short f32_to_bf16_rne(float f) {
    unsigned int u = __float_as_uint(f);
    unsigned int r = u + 0x7FFFu + ((u >> 16) & 1u);
    return (unsigned short)(r >> 16);
}

__device__ __forceinline__ void gload_lds16(const void* g, void* l) {
    __builtin_amdgcn_global_load_lds(
        (const __attribute__((address_space(1))) unsigned int*)g,
        (__attribute__((address_space(3))) unsigned int*)l, 16, 0, 0);
}

// ---------------------------------------------------------------------------
// Fused prep.
// Part A: repack h-slice of W2 (h==128: b2; h>=129: zeros) into fragment-major
//   bf16 bpf. cidx bits: ch<<10 | ks<<9 | g<<7 | sp<<6 | ll ; 16B chunk holds
//   B_h[k][col], col = 64ch+16g+(ll&15), k = 64ks+32sp+8(ll>>4)+j.
// Part B: hidden bf16-PAIRS into block-major slabs hTp2[eg][pair][80 edges].
//   W1/b1 via readfirstlane-pinned scalar path. pair64=(1,0), pair65=(0,0).
// Part C: h_w fp32 -> bf16 [e][j].
// Part D: zero d_out (for the K-split atomic combine).
// ---------------------------------------------------------------------------
__global__ __launch_bounds__(256) void prep_all(
    const float* __restrict__ W2, const float* __restrict__ b2,
    const float* __restrict__ ef, const float* __restrict__ W1,
    const float* __restrict__ b1, const float* __restrict__ hw,
    uint4* __restrict__ bpf, unsigned int* __restrict__ hTp2,
    unsigned short* __restrict__ hwb, float* __restrict__ outz)
{
    __shared__ __align__(16) char pmem[34816];
    const int bx = blockIdx.x;
    const int t  = threadIdx.x;

    if (bx < NBA) {
        const int h = bx;
        if (h < 129) {
            unsigned short* tile = (unsigned short*)pmem;   // [col][136]
            const float* src = (h < 128) ? (W2 + (size_t)h * (D_DIM * D_DIM)) : b2;
            #pragma unroll
            for (int r = 0; r < 16; ++r) {
                const float4 v = ((const float4*)src)[r * 256 + t];
                int c   = (r * 256 + t) * 4;
                int col = c >> 7;
                int k   = c & 127;
                unsigned int u0 = f32_to_bf16_rne(v.x) | ((unsigned int)f32_to_bf16_rne(v.y) << 16);
                unsigned int u1 = f32_to_bf16_rne(v.z) | ((unsigned int)f32_to_bf16_rne(v.w) << 16);
                *(uint2*)&tile[col * 136 + k] = make_uint2(u0, u1);
            }
            __syncthreads();
            #pragma unroll
            for (int r2 = 0; r2 < 8; ++r2) {
                int cidx = r2 * 256 + t;
                int ll = cidx & 63;
                int sp = (cidx >> 6) & 1;
                int gp = (cidx >> 7) & 3;
                int ks = (cidx >> 9) & 1;
                int ch = (cidx >> 10) & 1;
                int col = 64 * ch + 16 * gp + (ll & 15);
                int k0  = 64 * ks + 32 * sp + 8 * (ll >> 4);
                bpf[(size_t)h * 2048 + cidx] = *(const uint4*)&tile[col * 136 + k0];
            }
        } else {
            #pragma unroll
            for (int r2 = 0; r2 < 8; ++r2)
                bpf[(size_t)h * 2048 + r2 * 256 + t] = make_uint4(0, 0, 0, 0);
        }
    } else if (bx < NBA + NBH) {
        float (*lds_ef)[17] = (float(*)[17])pmem;
        const int b  = bx - NBA;
        const int e0 = b * 64;
        {
            int e  = t >> 2;
            int k4 = (t & 3) * 4;
            int ge = e0 + e;
            float4 v = make_float4(0.f, 0.f, 0.f, 0.f);
            if (ge < E_EDGES) v = *(const float4*)(ef + (size_t)ge * 16 + k4);
            lds_ef[e][k4 + 0] = v.x; lds_ef[e][k4 + 1] = v.y;
            lds_ef[e][k4 + 2] = v.z; lds_ef[e][k4 + 3] = v.w;
        }
        __syncthreads();
        const int e  = t & 63;
        const int hg = t >> 6;                // wave-uniform
        const int ge = e0 + e;
        const bool valid = ge < E_EDGES;
        const int eg = ge / 80;               // const-div -> magic mul
        const int re = ge - eg * 80;
        unsigned int* slab = hTp2 + (size_t)eg * SLAB_DW;
        float efr[16];
        #pragma unroll
        for (int k = 0; k < 16; ++k) efr[k] = lds_ef[e][k];
        #pragma unroll 4
        for (int hi2 = 0; hi2 < 16; ++hi2) {
            const int h0 = __builtin_amdgcn_readfirstlane(hg * 32 + 2 * hi2);
            float a0 = b1[h0], a1 = b1[h0 + 1];
            #pragma unroll
            for (int k = 0; k < 16; ++k) {
                a0 += efr[k] * W1[k * 128 + h0];
                a1 += efr[k] * W1[k * 128 + h0 + 1];
            }
            unsigned int pk = (unsigned int)f32_to_bf16_rne(fmaxf(a0, 0.f))
                            | ((unsigned int)f32_to_bf16_rne(fmaxf(a1, 0.f)) << 16);
            if (valid) slab[(hg * 16 + hi2) * 80 + re] = pk;
        }
        if (hg == 0 && valid) {
            slab[64 * 80 + re] = 0x00003F80u;   // (bf16 1.0, 0)  h=(128,129)
            slab[65 * 80 + re] = 0u;            // padding pair
        }
    } else if (bx < NBA + NBH + NBC) {
        int i0 = (bx - NBA - NBH) * 256 + t;
        for (int i = i0; i < (E_EDGES * D_DIM) / 4; i += NBC * 256) {
            const float4 v = ((const float4*)hw)[i];
            union { unsigned short u16[4]; uint2 u2; } o;
            o.u16[0] = f32_to_bf16_rne(v.x);
            o.u16[1] = f32_to_bf16_rne(v.y);
            o.u16[2] = f32_to_bf16_rne(v.z);
            o.u16[3] = f32_to_bf16_rne(v.w);
            ((uint2*)hwb)[i] = o.u2;
        }
    } else {
        int i0 = (bx - NBA - NBH - NBC) * 256 + t;
        float4* o4 = (float4*)outz;
        for (int i = i0; i < (E_EDGES * D_DIM) / 4; i += NBD * 256)
            o4[i] = make_float4(0.f, 0.f, 0.f, 0.f);
    }
}

// ---------------------------------------------------------------------------
// Main: 1000 blocks x 256 threads (4 waves). Block = 80 edges x 64 cols x 64 j.
// bx -> eg = bx>>2 (0..249), ch = (bx>>1)&1, ks = bx&1 ; (ch,ks) is constant
// per XCD (bx%8) -> 1.06 MB B working set per XCD L2.
// Wave w: col-group g=w (16 cols): 5 m-tiles x K64 = 10 MFMAs per h-step.
// Hidden slab (21.5 KB) DMA'd to LDS ONCE; h-loop is BARRIER-FREE:
// B double-buffered in regs from L2, hp via broadcast ds_read_b128.
// __launch_bounds__(256,4): 4 blocks/CU (CUDA semantics) -> 16 waves/CU,
// VGPR cap 128 (est. need ~118). K-halves combined via fp32 atomicAdd.
// ---------------------------------------------------------------------------
__global__ __launch_bounds__(256, 4)
void edge_main(const uint4* __restrict__ bpf, const unsigned int* __restrict__ hTp2,
               const uint4* __restrict__ hwb, float* __restrict__ out) {
    __shared__ __align__(16) char slab[21504];
    const int bx  = blockIdx.x;
    const int eg  = bx >> 2;
    const int ch  = (bx >> 1) & 1;
    const int ks  = bx & 1;
    const int tid = threadIdx.x;
    const int w   = tid >> 6;
    const int l   = tid & 63;
    const int l4  = l >> 4;
    const int lm  = l & 15;
    const int e0  = eg * 80;

    // DMA hidden slab for these 80 edges into LDS (21 x 1KB, spread over waves)
    {
        const char* src = (const char*)(hTp2 + (size_t)eg * SLAB_DW);
        for (int i = w; i < 21; i += 4)
            gload_lds16(src + i * 1024 + l * 16, slab + i * 1024);
    }

    // resident A frags (j-half ks): A[m][sp] = hw[e0+16m+lm][64ks+32sp+8*l4 ..+7]
    bf16x8 A[5][2];
    #pragma unroll
    for (int m = 0; m < 5; ++m)
        #pragma unroll
        for (int sp = 0; sp < 2; ++sp)
            A[m][sp] = ((const bf16x8*)hwb)[(e0 + 16 * m + lm) * 16 + 8 * ks + 4 * sp + l4];

    floatx4 C[5];
    #pragma unroll
    for (int m = 0; m < 5; ++m) C[m] = (floatx4){0.f, 0.f, 0.f, 0.f};
    const floatx4 Zf = (floatx4){0.f, 0.f, 0.f, 0.f};

    __syncthreads();    // slab DMA drained (vmcnt(0) implied); ONLY barrier

    const bf16x8* bpf8 = (const bf16x8*)bpf;
    const int cbase = ch * 1024 + ks * 512 + w * 128 + l;   // 16B-chunk offset within h

    bf16x8 Ba[2], Bb[2];
    auto loadB = [&](int h, bf16x8 (&B)[2]) {
        const bf16x8* p = bpf8 + (size_t)h * 2048 + cbase;
        B[0] = p[0];
        B[1] = p[64];
    };
    auto computeH = [&](const bf16x8 (&B)[2], const uint4 (&hp)[5], bool odd) {
        #pragma unroll
        for (int m = 0; m < 5; ++m) {
            floatx4 D = __builtin_amdgcn_mfma_f32_16x16x32_bf16(A[m][0], B[0], Zf, 0, 0, 0);
            D = __builtin_amdgcn_mfma_f32_16x16x32_bf16(A[m][1], B[1], D, 0, 0, 0);
            #pragma unroll
            for (int r = 0; r < 4; ++r) {
                unsigned int u = hp[m][r];
                float sc = odd ? __uint_as_float(u & 0xFFFF0000u)
                               : __uint_as_float(u << 16);
                C[m][r] += sc * D[r];
            }
        }
    };

    loadB(0, Ba);
    for (int q = 0; q < 65; ++q) {            // pair q -> h = 2q, 2q+1
        uint4 hp[5];
        #pragma unroll
        for (int m = 0; m < 5; ++m)           // broadcast reads (lm ignored)
            hp[m] = *(const uint4*)(slab + q * 320 + m * 64 + l4 * 16);
        loadB(2 * q + 1, Bb);
        computeH(Ba, hp, false);
        loadB(2 * q + 2, Ba);                 // q=64 -> h=130: zero slice
        computeH(Bb, hp, true);
    }

    // epilogue: C/D layout col = lane&15, row = 4*(lane>>4)+r ; combine K-split
    #pragma unroll
    for (int m = 0; m < 5; ++m)
        #pragma unroll
        for (int r = 0; r < 4; ++r)
            atomicAdd(&out[(size_t)(e0 + 16 * m + 4 * l4 + r) * D_DIM
                           + 64 * ch + 16 * w + lm], C[m][r]);
}

// ---------------------------------------------------------------------------
extern "C" void kernel_launch(void* const* d_in, const int* in_sizes, int n_in,
                              void* d_out, int out_size, void* d_ws, size_t ws_size,
                              hipStream_t stream) {
    // inputs: h_v, h_w, edge_features, W1, b1, W2, b2 (fp32; h_v unused)
    const float* h_w = (const float*)d_in[1];
    const float* ef  = (const float*)d_in[2];
    const float* W1  = (const float*)d_in[3];
    const float* b1  = (const float*)d_in[4];
    const float* W2  = (const float*)d_in[5];
    const float* b2  = (const float*)d_in[6];
    float* out = (float*)d_out;

    char* ws = (char*)d_ws;
    uint4*          bpf  = (uint4*)ws;                                  // 132*32768 = 4,325,376 B
    unsigned int*   hTp2 = (unsigned int*)(ws + 4325376);               // 251*21504 = 5,397,504 B
    unsigned short* hwb  = (unsigned short*)(ws + 4325376 + 5397504);   // 5,120,000 B
    // total ws use: 14,842,880 B

    hipLaunchKernelGGL(prep_all, dim3(NBA + NBH + NBC + NBD), dim3(256), 0, stream,
                       W2, b2, ef, W1, b1, h_w, bpf, hTp2, hwb, out);
    hipLaunchKernelGGL(edge_main, dim3(1000), dim3(256), 0, stream,
                       bpf, hTp2, (const uint4*)hwb, out);
}

// Round 6
// 180.453 us; speedup vs baseline: 2.8684x; 1.0399x over previous
//
#include <hip/hip_runtime.h>

#define E_EDGES 20000
#define D_DIM   128

// prep grid layout
#define NBA 132               // W2/b2 repack: one h-slice per block (128 W2 + bias + 3 zero)
#define NBH 313               // hidden: ceil(20000/64) edge-blocks
#define NBC 320               // h_w fp32->fp16, grid-stride
#define NBD 250               // zero d_out, grid-stride

#define SLAB_B  21504         // per-eg hidden slab bytes (80 e x 132 h x 2B = 21120, pad to 21*1024)
#define BPF_SL  136           // bpf h-slices allocated (132 written; 133-135 prefetch pad)

typedef _Float16 f16x8 __attribute__((ext_vector_type(8)));
typedef _Float16 f16x2 __attribute__((ext_vector_type(2)));
typedef float    floatx4 __attribute__((ext_vector_type(4)));

union F8 { f16x8 v; f16x2 h2[4]; unsigned int u[4]; };

__device__ __forceinline__ unsigned short f32_to_f16(float f) {
    _Float16 h = (_Float16)f;                       // v_cvt_f16_f32 (RNE)
    return __builtin_bit_cast(unsigned short, h);
}

__device__ __forceinline__ void gload_lds16(const void* g, void* l) {
    __builtin_amdgcn_global_load_lds(
        (const __attribute__((address_space(1))) unsigned int*)g,
        (__attribute__((address_space(3))) unsigned int*)l, 16, 0, 0);
}

// ---------------------------------------------------------------------------
// Fused prep.
// Part A: repack h-slice of W2 (h==128: b2; h 129..131: zeros) into
//   fragment-major fp16 bpf. cidx bits: ch<<10|ks<<9|g<<7|sp<<6|ll; chunk j:
//   B_h[k][col], col = 64ch+16g+(ll&15), k = 64ks+32sp+8(ll>>4)+j.
// Part B: hidden fp16 slabs hslab[eg][edge 0..79][h 0..131] (edge stride 264B).
//   relu(ef@W1+b1) via LDS-staged W1 (broadcast reads); h=128 ->1.0, 129..131 ->0.
// Part C: h_w fp32 -> fp16 [e][j].
// Part D: zero d_out (for the K-split atomic combine).
// ---------------------------------------------------------------------------
__global__ __launch_bounds__(256) void prep_all(
    const float* __restrict__ W2, const float* __restrict__ b2,
    const float* __restrict__ ef, const float* __restrict__ W1,
    const float* __restrict__ b1, const float* __restrict__ hw,
    uint4* __restrict__ bpf, char* __restrict__ hslab,
    unsigned short* __restrict__ hwb, float* __restrict__ outz)
{
    __shared__ __align__(16) char pmem[34816];
    const int bx = blockIdx.x;
    const int t  = threadIdx.x;

    if (bx < NBA) {
        const int h = bx;
        if (h < 129) {
            unsigned short* tile = (unsigned short*)pmem;   // [col][136]
            const float* src = (h < 128) ? (W2 + (size_t)h * (D_DIM * D_DIM)) : b2;
            #pragma unroll
            for (int r = 0; r < 16; ++r) {
                const float4 v = ((const float4*)src)[r * 256 + t];
                int c   = (r * 256 + t) * 4;
                int col = c >> 7;
                int k   = c & 127;
                unsigned int u0 = f32_to_f16(v.x) | ((unsigned int)f32_to_f16(v.y) << 16);
                unsigned int u1 = f32_to_f16(v.z) | ((unsigned int)f32_to_f16(v.w) << 16);
                *(uint2*)&tile[col * 136 + k] = make_uint2(u0, u1);
            }
            __syncthreads();
            #pragma unroll
            for (int r2 = 0; r2 < 8; ++r2) {
                int cidx = r2 * 256 + t;
                int ll = cidx & 63;
                int sp = (cidx >> 6) & 1;
                int gp = (cidx >> 7) & 3;
                int ks = (cidx >> 9) & 1;
                int ch = (cidx >> 10) & 1;
                int col = 64 * ch + 16 * gp + (ll & 15);
                int k0  = 64 * ks + 32 * sp + 8 * (ll >> 4);
                bpf[(size_t)h * 2048 + cidx] = *(const uint4*)&tile[col * 136 + k0];
            }
        } else {
            #pragma unroll
            for (int r2 = 0; r2 < 8; ++r2)
                bpf[(size_t)h * 2048 + r2 * 256 + t] = make_uint4(0, 0, 0, 0);
        }
    } else if (bx < NBA + NBH) {
        // LDS: W1s 16x128 f32 (8KB) | b1s 128 f32 (512B) | efs 64x17 f32 (4352B)
        float* W1s = (float*)pmem;
        float* b1s = (float*)(pmem + 8192);
        float (*efs)[17] = (float(*)[17])(pmem + 8704);
        const int b  = bx - NBA;
        const int e0 = b * 64;
        #pragma unroll
        for (int i = 0; i < 2; ++i)
            *(float4*)&W1s[(i * 256 + t) * 4] = ((const float4*)W1)[i * 256 + t];
        if (t < 32) *(float4*)&b1s[t * 4] = ((const float4*)b1)[t];
        {
            int e  = t >> 2;
            int k4 = (t & 3) * 4;
            int ge = e0 + e;
            float4 v = make_float4(0.f, 0.f, 0.f, 0.f);
            if (ge < E_EDGES) v = *(const float4*)(ef + (size_t)ge * 16 + k4);
            efs[e][k4 + 0] = v.x; efs[e][k4 + 1] = v.y;
            efs[e][k4 + 2] = v.z; efs[e][k4 + 3] = v.w;
        }
        __syncthreads();
        const int e  = t & 63;
        const int hg = t >> 6;                 // wave-uniform
        const int ge = e0 + e;
        const bool valid = ge < E_EDGES;
        const int eg = ge / 80;                // magic-mul
        const int re = ge - eg * 80;
        char* slab = hslab + (size_t)eg * SLAB_B + re * 264;
        float efr[16];
        #pragma unroll
        for (int k = 0; k < 16; ++k) efr[k] = efs[e][k];
        #pragma unroll 4
        for (int hi2 = 0; hi2 < 16; ++hi2) {
            const int h0 = hg * 32 + 2 * hi2;
            float2 bb = *(const float2*)&b1s[h0];
            float a0 = bb.x, a1 = bb.y;
            #pragma unroll
            for (int k = 0; k < 16; ++k) {
                float2 wv = *(const float2*)&W1s[k * 128 + h0];   // broadcast
                a0 += efr[k] * wv.x;
                a1 += efr[k] * wv.y;
            }
            unsigned int pk = (unsigned int)f32_to_f16(fmaxf(a0, 0.f))
                            | ((unsigned int)f32_to_f16(fmaxf(a1, 0.f)) << 16);
            if (valid) *(unsigned int*)(slab + h0 * 2) = pk;
        }
        if (hg == 0 && valid) {
            *(unsigned int*)(slab + 128 * 2) = 0x00003C00u;   // (fp16 1.0, 0) h=128,129
            *(unsigned int*)(slab + 130 * 2) = 0u;            // h=130,131
        }
    } else if (bx < NBA + NBH + NBC) {
        int i0 = (bx - NBA - NBH) * 256 + t;
        for (int i = i0; i < (E_EDGES * D_DIM) / 4; i += NBC * 256) {
            const float4 v = ((const float4*)hw)[i];
            union { unsigned short u16[4]; uint2 u2; } o;
            o.u16[0] = f32_to_f16(v.x);
            o.u16[1] = f32_to_f16(v.y);
            o.u16[2] = f32_to_f16(v.z);
            o.u16[3] = f32_to_f16(v.w);
            ((uint2*)hwb)[i] = o.u2;
        }
    } else {
        int i0 = (bx - NBA - NBH - NBC) * 256 + t;
        float4* o4 = (float4*)outz;
        for (int i = i0; i < (E_EDGES * D_DIM) / 4; i += NBD * 256)
            o4[i] = make_float4(0.f, 0.f, 0.f, 0.f);
    }
}

// ---------------------------------------------------------------------------
// Main (Z-GEMM): 1000 blocks x 256 threads. Block = 80 edges x 64 cols x 64 j.
// eg = bx>>2, ch = (bx>>1)&1, ks = bx&1 (XCD-pinned -> 1.06MB B set per XCD L2).
// messages = Z @ W2flat^T, Z[e,(h,j)] = hidden[e,h]*hw[e,j] formed in regs as
// fp16 (v_pk_mul_f16); C accumulates in MFMA accumulator across ALL h — no
// per-h VALU epilogue, no MFMA->VALU dependency chain. Hidden slab (21KB fp16)
// DMA'd to LDS once; h-loop barrier-free; B double-buffered from L2
// (prefetch distance 2). K-halves combined via fp32 atomicAdd.
// ---------------------------------------------------------------------------
__global__ __launch_bounds__(256, 4)
void edge_main(const uint4* __restrict__ bpf, const char* __restrict__ hslab,
               const uint4* __restrict__ hwb, float* __restrict__ out) {
    __shared__ __align__(16) char slab[SLAB_B];
    const int bx  = blockIdx.x;
    const int eg  = bx >> 2;
    const int ch  = (bx >> 1) & 1;
    const int ks  = bx & 1;
    const int tid = threadIdx.x;
    const int w   = tid >> 6;
    const int l   = tid & 63;
    const int l4  = l >> 4;
    const int lm  = l & 15;
    const int e0  = eg * 80;

    // DMA hidden slab (80 edges x 132 h fp16) into LDS: 21 x 1KB
    {
        const char* src = hslab + (size_t)eg * SLAB_B;
        for (int i = w; i < 21; i += 4)
            gload_lds16(src + i * 1024 + l * 16, slab + i * 1024);
    }

    // resident A-source (fp16 h_w): hwh[m][jq] = hw[e0+16m+lm][64ks+32jq+8*l4 ..+7]
    F8 hwh[5][2];
    #pragma unroll
    for (int m = 0; m < 5; ++m)
        #pragma unroll
        for (int jq = 0; jq < 2; ++jq)
            hwh[m][jq].v = ((const F8*)hwb)[(e0 + 16 * m + lm) * 16 + 8 * ks + 4 * jq + l4].v;

    floatx4 C[5];
    #pragma unroll
    for (int m = 0; m < 5; ++m) C[m] = (floatx4){0.f, 0.f, 0.f, 0.f};

    __syncthreads();    // slab DMA drained; ONLY barrier

    const f16x8* bpf8 = (const f16x8*)bpf;
    const int cbase = ch * 1024 + ks * 512 + w * 128 + l;   // 16B-chunk idx within h-slice

    f16x8 Bbuf[2][2];
    auto loadB = [&](int h, f16x8 (&B)[2]) {
        const f16x8* p = bpf8 + (size_t)h * 2048 + cbase;
        B[0] = p[0];
        B[1] = p[64];
    };
    auto loadHid = [&](int h4, uint2 (&hid)[5]) {
        #pragma unroll
        for (int m = 0; m < 5; ++m)
            hid[m] = *(const uint2*)(slab + (16 * m + lm) * 264 + h4 * 8);
    };
    // one h-step: form A' = hwh * hidden[e,h] (packed fp16), 2 MFMAs per m
    auto group4 = [&](int h4, const uint2 (&hid)[5]) {
        #pragma unroll
        for (int hh = 0; hh < 4; ++hh) {
            const int h = 4 * h4 + hh;
            const int p = h & 1;
            f16x2 d[5];
            #pragma unroll
            for (int m = 0; m < 5; ++m) {
                unsigned int s   = (hh < 2) ? hid[m].x : hid[m].y;
                unsigned int sel = (hh & 1) ? 0x03020302u : 0x01000100u;
                d[m] = __builtin_bit_cast(f16x2, __builtin_amdgcn_perm(0u, s, sel));
            }
            #pragma unroll
            for (int m = 0; m < 5; ++m) {
                F8 a0, a1;
                #pragma unroll
                for (int i = 0; i < 4; ++i) {
                    a0.h2[i] = hwh[m][0].h2[i] * d[m];
                    a1.h2[i] = hwh[m][1].h2[i] * d[m];
                }
                C[m] = __builtin_amdgcn_mfma_f32_16x16x32_f16(a0.v, Bbuf[p][0], C[m], 0, 0, 0);
                C[m] = __builtin_amdgcn_mfma_f32_16x16x32_f16(a1.v, Bbuf[p][1], C[m], 0, 0, 0);
            }
            loadB(h + 2, Bbuf[p]);    // refill (prefetch distance 2; h+2 <= 133 < 136 pad)
        }
    };

    loadB(0, Bbuf[0]);
    loadB(1, Bbuf[1]);
    uint2 hidA[5], hidB[5];
    loadHid(0, hidA);
    for (int h4 = 0; h4 < 32; h4 += 2) {
        loadHid(h4 + 1, hidB);
        group4(h4, hidA);
        loadHid(h4 + 2, hidA);
        group4(h4 + 1, hidB);
    }
    group4(32, hidA);    // h = 128..131 (bias row + zero rows)

    // epilogue: C/D layout col = lane&15, row = 4*(lane>>4)+r ; combine K-split
    #pragma unroll
    for (int m = 0; m < 5; ++m)
        #pragma unroll
        for (int r = 0; r < 4; ++r)
            atomicAdd(&out[(size_t)(e0 + 16 * m + 4 * l4 + r) * D_DIM
                           + 64 * ch + 16 * w + lm], C[m][r]);
}

// ---------------------------------------------------------------------------
extern "C" void kernel_launch(void* const* d_in, const int* in_sizes, int n_in,
                              void* d_out, int out_size, void* d_ws, size_t ws_size,
                              hipStream_t stream) {
    // inputs: h_v, h_w, edge_features, W1, b1, W2, b2 (fp32; h_v unused)
    const float* h_w = (const float*)d_in[1];
    const float* ef  = (const float*)d_in[2];
    const float* W1  = (const float*)d_in[3];
    const float* b1  = (const float*)d_in[4];
    const float* W2  = (const float*)d_in[5];
    const float* b2  = (const float*)d_in[6];
    float* out = (float*)d_out;

    char* ws = (char*)d_ws;
    uint4*          bpf   = (uint4*)ws;                                // 136*32768 = 4,456,448 B
    char*           hslab = ws + 4456448;                              // 250*21504 = 5,376,000 B
    unsigned short* hwb   = (unsigned short*)(ws + 4456448 + 5376000); // 5,120,000 B
    // total ws use: 14,952,448 B

    hipLaunchKernelGGL(prep_all, dim3(NBA + NBH + NBC + NBD), dim3(256), 0, stream,
                       W2, b2, ef, W1, b1, h_w, bpf, hslab, hwb, out);
    hipLaunchKernelGGL(edge_main, dim3(1000), dim3(256), 0, stream,
                       bpf, hslab, (const uint4*)hwb, out);
}